// Round 13
// baseline (3801.734 us; speedup 1.0000x reference)
//
#include <hip/hip_runtime.h>
#include <stdint.h>

// B=32, S=512, I=H=O=1024, L=2.  Pipeline: gang0 -> xgang -> gang1 -> ygang,
// batch-halves G0/G1 interleaved.  R13: chain producers (rh, h) store via
// per-wave LDS transpose as 16B sc-stores (8x fewer stores, faster ack).

typedef __bf16 bf16x8 __attribute__((ext_vector_type(8)));
typedef float f32x4 __attribute__((ext_vector_type(4)));
typedef unsigned short u16;
typedef unsigned int u32;
typedef u32 u32x2 __attribute__((ext_vector_type(2)));
typedef u32 u32x4 __attribute__((ext_vector_type(4)));

typedef __attribute__((address_space(1))) u32 as1_u32;
typedef __attribute__((address_space(3))) u32 as3_u32;

__device__ __forceinline__ u16 f2bf(float f) {
  union { float f; u32 u; } a; a.f = f;
  u32 u = a.u;
  u32 r = (u + 0x7fffu + ((u >> 16) & 1u)) >> 16;  // RNE
  return (u16)r;
}
__device__ __forceinline__ float bf2f(u16 b) {
  union { u32 u; float f; } a; a.u = ((u32)b) << 16;
  return a.f;
}
__device__ __forceinline__ float sigmoidf_(float x) {
  return 1.0f / (1.0f + __expf(-x));
}
__device__ __forceinline__ bf16x8 as_bf(u32x4 q) {
  union { u32x4 q; bf16x8 v; } u; u.q = q; return u.v;
}

#define MFMA16(a, b, c) __builtin_amdgcn_mfma_f32_16x16x32_bf16((a), (b), (c), 0, 0, 0)

// async global->LDS, 16B per lane (GEMM staging only; cached path)
__device__ __forceinline__ void gll16(const void* g, void* l) {
  __builtin_amdgcn_global_load_lds((as1_u32*)g, (as3_u32*)l, 16, 0, 0);
}

// ---------------- sc0sc1 (L3-coherent, cross-XCD) memory ops — proven ----------------
__device__ __forceinline__ u32x4 ld_sc16(const void* p) {
  u32x4 r;
  asm volatile("global_load_dwordx4 %0, %1, off sc0 sc1" : "=v"(r) : "v"(p) : "memory");
  return r;
}
__device__ __forceinline__ u32x2 ld_sc8(const void* p) {
  u32x2 r;
  asm volatile("global_load_dwordx2 %0, %1, off sc0 sc1" : "=v"(r) : "v"(p) : "memory");
  return r;
}
__device__ __forceinline__ void st_sc8(void* p, u32x2 v) {
  asm volatile("global_store_dwordx2 %0, %1, off sc0 sc1" :: "v"(p), "v"(v) : "memory");
}
__device__ __forceinline__ void st_sc16(void* p, u32x4 v) {
  asm volatile("global_store_dwordx4 %0, %1, off sc0 sc1" :: "v"(p), "v"(v) : "memory");
}
__device__ __forceinline__ void wait_vm0() {
  asm volatile("s_waitcnt vmcnt(0)" ::: "memory");
  __builtin_amdgcn_sched_barrier(0);  // rule #18
}
__device__ __forceinline__ int ldflag(const int* p) {
  int r;
  asm volatile("global_load_dword %0, %1, off sc0 sc1\n\ts_waitcnt vmcnt(0)"
               : "=v"(r) : "v"(p) : "memory");
  return r;
}
__device__ __forceinline__ void stflag(int* p, int v) {
  asm volatile("global_store_dword %0, %1, off sc0 sc1" :: "v"(p), "v"(v) : "memory");
}

// ---------------- flag sync: monotonic counters, one 128B line per flag ----------------
__device__ __forceinline__ void signal_flag(int* flag, int val) {
  asm volatile("s_waitcnt vmcnt(0)" ::: "memory");  // our sc stores acked at L3
  __syncthreads();                                  // all waves done
  if (threadIdx.x == 0) stflag(flag, val);
}
__device__ __forceinline__ void wait_flags(int* flags, int nf, int target, int tid) {
  if (tid < 64) {
    for (;;) {
      int v = (tid < nf) ? ldflag(flags + tid * 32) : target;
      if (__all(v >= target)) break;
      __builtin_amdgcn_s_sleep(2);
    }
  }
  __syncthreads();
}
// two flag groups, independent targets (t<=0 auto-satisfied; flags start at 0)
__device__ __forceinline__ void wait_flags2(int* f1, int n1, int t1,
                                            int* f2, int n2, int t2, int tid) {
  if (tid < 64) {
    const int* addr = nullptr;
    int tgt = 0, active = 0;
    if (tid < n1) { addr = f1 + tid * 32; tgt = t1; active = 1; }
    else if (tid < n1 + n2) { addr = f2 + (tid - n1) * 32; tgt = t2; active = 1; }
    for (;;) {
      int v = active ? ldflag(addr) : 0;
      int sat = (!active) || (v >= tgt);
      if (__all(sat)) break;
      __builtin_amdgcn_s_sleep(2);
    }
  }
  __syncthreads();
}

// Stage a [16][1024] bf16 matrix (32 KB) global->LDS, sc-coherent, reg-staged.
// LDS chunk (row, sc) <- global chunk (row, sc ^ (row&7))  (16B chunks).
__device__ __forceinline__ void stage_issue16(const u16* g, u32x4* v, int tid) {
#pragma unroll
  for (int it = 0; it < 4; ++it) {
    int cc = tid + it * 512;          // 16B-chunk id 0..2047
    int row = cc >> 7, sc = cc & 127;
    int gsc = sc ^ (row & 7);
    v[it] = ld_sc16((const char*)g + (size_t)(row * 128 + gsc) * 16);
  }
}
__device__ __forceinline__ void stage_write16(u16* lds, const u32x4* v, int tid) {
#pragma unroll
  for (int it = 0; it < 4; ++it) {
    int cc = tid + it * 512;
    *(u32x4*)((char*)lds + (size_t)cc * 16) = v[it];
  }
}
__device__ __forceinline__ u32x4 read_frag_sw(const u16* lds, int row, int kt, int hi4) {
  int cc = kt * 4 + hi4;
  int sc = cc ^ (row & 7);
  return *(const u32x4*)((const char*)lds + (size_t)row * 2048 + (size_t)sc * 16);
}

// per-wave 16x16 u16 transpose region in (free) staging LDS, then 16B sc-stores.
// vals[j] belongs to row (hi4*4+j), col `col` of the wave's 16x16 tile.
// dst row-major [16][1024] at column base `cb`.
__device__ __forceinline__ void store_tile_wide(u16* smem, int wv, int col, int hi4,
                                                const u16* vals, u16* dst, int cb,
                                                int lane) {
  __syncthreads();  // all waves done reading staged data in smem
  u16* tp = smem + wv * 256;
#pragma unroll
  for (int j = 0; j < 4; ++j) tp[(hi4 * 4 + j) * 16 + col] = vals[j];
  __syncthreads();
  if (lane < 32) {
    int row = lane >> 1, half = lane & 1;
    u32x4 q = *(const u32x4*)(tp + row * 16 + half * 8);
    st_sc16(dst + (size_t)row * 1024 + cb + half * 8, q);
  }
}

// xpv: cached strided loads from xproj [512][32][3072]
__device__ __forceinline__ void load_xpv4(float* xpv, const u16* xproj, int s,
                                          int n_g, int b0) {
  const u16* xb = xproj + (size_t)s * (32 * 3072) + (size_t)b0 * 3072 + n_g;
#pragma unroll
  for (int j = 0; j < 4; ++j) xpv[j] = bf2f(xb[(size_t)j * 3072]);
}

// load persistent weight fragments: row n_g of W (row-major [.][1024] bf16)
__device__ __forceinline__ void load_Bf(u32x4* Bf, const u16* W, int n_g, int hi4) {
  const u16* wrow = W + (size_t)n_g * 1024 + 8 * hi4;
#pragma unroll
  for (int kt = 0; kt < 32; ++kt) Bf[kt] = *(const u32x4*)(wrow + kt * 32);
}

// ---------------- pipelined GRU kernel (both layers + x-proj + out-proj) ----------------
// grid = 80 wgs x 512 thr:
//   wg  0..15 : gang0 zr (z:0..7, r:8..15)  layer0
//   wg 16..23 : gang0 g                      layer0; writes h0ring
//   wg 24..47 : xgang (xp1 = h0 @ Wx1^T+bx1)
//   wg 48..63 : gang1 zr                     layer1
//   wg 64..71 : gang1 g                      layer1; writes h1ring/hidden
//   wg 72..79 : ygang (out = h1 @ Why^T+bhy) -> d_out (cached f32)
// Per-group flag regions (128B-padded ints):
//   A0 = bar + g*512 (16) | B0 = bar+1024+g*256 (8) | A1 = bar+1536+g*512 (16)
//   B1 = bar+2560+g*256 (8) | X = bar+3072+g*768 (24) | Y = bar+4608+g*256 (8)
__global__ __launch_bounds__(512, 1) void gru_pipe_kernel(
    const u16* __restrict__ xproj,   // [512][32][3072] layer0 x-projection
    const u16* __restrict__ Whb,     // [2][3072][1024]
    const u16* __restrict__ Wx1,     // [3072][1024] (layer1)
    const float* __restrict__ bx,    // [2][3072]
    const float* __restrict__ h0in,  // [32][2][1024]
    u16* __restrict__ h0ring,        // [2][4][16][1024]
    u16* __restrict__ h1ring,        // [2][4][16][1024]
    u16* __restrict__ rh0,           // [2][16][1024]
    u16* __restrict__ rh1,           // [2][16][1024]
    float* __restrict__ z0_t,        // [2][1024][16]
    float* __restrict__ z1_t,        // [2][1024][16]
    u16* __restrict__ xp1t,          // [2][4][3072][16]
    const u16* __restrict__ Why,     // [1024][1024] bf16
    const float* __restrict__ bhy,   // [1024]
    float* __restrict__ outp,        // [32][512][1024] f32 (d_out head)
    float* __restrict__ hidden,      // [32][2][1024] (d_out tail)
    int* __restrict__ bar)
{
  __shared__ u16 smem[16 * 1024];  // 32 KB staging (+ transpose scratch reuse)
  const int tid = (int)threadIdx.x;
  const int lane = tid & 63;
  const int wv = tid >> 6;
  const int wg = (int)blockIdx.x;
  const int col = lane & 15;
  const int hi4 = lane >> 4;

  int* A0 = bar;
  int* B0 = bar + 1024;
  int* A1 = bar + 1536;
  int* B1 = bar + 2560;
  int* X  = bar + 3072;
  int* Y  = bar + 4608;

  if (wg < 16) {
    // ================= gang0 zr (layer0) =================
    const int gw = wg * 8 + wv;          // 0..127
    const int n_g = gw * 16 + col;       // 0..2047
    const bool is_z = (wg < 8);
    const int rc = n_g - 1024;
    u32x4 Bf[32];
    load_Bf(Bf, Whb, n_g, hi4);
    for (int s = 0; s < 512; ++s) {
#pragma unroll
      for (int g2 = 0; g2 < 2; ++g2) {
        float xpv[4];
        load_xpv4(xpv, xproj, s, n_g, g2 * 16 + hi4 * 4);
        wait_flags(B0 + g2 * 256, 8, s, tid);  // h_g(s-1) stored
        u32x4 v[4];
        stage_issue16(h0ring + g2 * 65536 + (size_t)((s - 1) & 3) * 16384, v, tid);
        wait_vm0();
        stage_write16(smem, v, tid);
        __syncthreads();
        f32x4 acc = {0.f, 0.f, 0.f, 0.f};
#pragma unroll
        for (int kt = 0; kt < 32; ++kt)
          acc = MFMA16(as_bf(read_frag_sw(smem, col, kt, hi4)), as_bf(Bf[kt]), acc);
        if (is_z) {
          union { float f[4]; u32x4 q; } q0;
#pragma unroll
          for (int j = 0; j < 4; ++j) q0.f[j] = sigmoidf_(xpv[j] + acc[j]);
          st_sc16(&z0_t[g2 * 16384 + n_g * 16 + hi4 * 4], q0.q);
        } else {
          u16 rhv[4];
#pragma unroll
          for (int j = 0; j < 4; ++j) {
            int bl = hi4 * 4 + j;
            float rv = sigmoidf_(xpv[j] + acc[j]);
            u16 hraw = smem[bl * 1024 + ((((rc >> 3) ^ (bl & 7)) << 3) | (rc & 7))];
            rhv[j] = f2bf(rv * bf2f(hraw));
          }
          store_tile_wide(smem, wv, col, hi4, rhv,
                          rh0 + g2 * 16384, gw * 16 - 1024, lane);
        }
        signal_flag(&A0[g2 * 512 + wg * 32], s + 1);
      }
    }
  } else if (wg < 24) {
    // ================= gang0 g (layer0) =================
    const int wgl = wg - 16;             // 0..7
    const int gw = 128 + wgl * 8 + wv;   // 128..191
    const int n_g = gw * 16 + col;       // 2048..3071
    const int gc = n_g - 2048;
    u32x4 Bf[32];
    load_Bf(Bf, Whb, n_g, hi4);
    float h_reg[2][4];
#pragma unroll
    for (int g2 = 0; g2 < 2; ++g2)
#pragma unroll
      for (int j = 0; j < 4; ++j)
        h_reg[g2][j] = h0in[(g2 * 16 + hi4 * 4 + j) * 2048 + gc];
    for (int s = 0; s < 512; ++s) {
#pragma unroll
      for (int g2 = 0; g2 < 2; ++g2) {
        float xpv[4];
        load_xpv4(xpv, xproj, s, n_g, g2 * 16 + hi4 * 4);
        wait_flags2(A0 + g2 * 512, 16, s + 1, X + g2 * 768, 24, s - 3, tid);
        u32x4 v[4];
        stage_issue16(rh0 + g2 * 16384, v, tid);
        u32x4 zq = ld_sc16(&z0_t[g2 * 16384 + gc * 16 + hi4 * 4]);
        wait_vm0();
        stage_write16(smem, v, tid);
        __syncthreads();
        f32x4 acc = {0.f, 0.f, 0.f, 0.f};
#pragma unroll
        for (int kt = 0; kt < 32; ++kt)
          acc = MFMA16(as_bf(read_frag_sw(smem, col, kt, hi4)), as_bf(Bf[kt]), acc);
        union { u32x4 q; float f[4]; } zz; zz.q = zq;
        u16 hv[4];
#pragma unroll
        for (int j = 0; j < 4; ++j) {
          float gv = sigmoidf_(xpv[j] + acc[j]);
          float hn = zz.f[j] * h_reg[g2][j] + (1.0f - zz.f[j]) * gv;
          h_reg[g2][j] = hn;
          hv[j] = f2bf(hn);
        }
        store_tile_wide(smem, wv, col, hi4, hv,
                        h0ring + g2 * 65536 + (size_t)(s & 3) * 16384,
                        gw * 16 - 2048, lane);
        signal_flag(&B0[g2 * 256 + wgl * 32], s + 1);
        if (s == 511) {
#pragma unroll
          for (int j = 0; j < 4; ++j)
            hidden[(g2 * 16 + hi4 * 4 + j) * 2048 + gc] = h_reg[g2][j];
        }
      }
    }
  } else if (wg < 48) {
    // ================= xgang: xp1(t) = h0(t) @ Wx1^T + bx1 =================
    const int wgx = wg - 24;             // 0..23
    const int gw = wgx * 8 + wv;         // 0..191
    const int n_g = gw * 16 + col;       // 0..3071
    u32x4 Bf[32];
    load_Bf(Bf, Wx1, n_g, hi4);
    const float bias = bx[3072 + n_g];
    for (int t = 0; t < 512; ++t) {
#pragma unroll
      for (int g2 = 0; g2 < 2; ++g2) {
        wait_flags2(B0 + g2 * 256, 8, t + 1, B1 + g2 * 256, 8, t - 3, tid);
        u32x4 v[4];
        stage_issue16(h0ring + g2 * 65536 + (size_t)(t & 3) * 16384, v, tid);
        wait_vm0();
        stage_write16(smem, v, tid);
        __syncthreads();
        f32x4 acc = {0.f, 0.f, 0.f, 0.f};
#pragma unroll
        for (int kt = 0; kt < 32; ++kt)
          acc = MFMA16(as_bf(read_frag_sw(smem, col, kt, hi4)), as_bf(Bf[kt]), acc);
        union { u16 o[4]; u32x2 q; } p;
#pragma unroll
        for (int j = 0; j < 4; ++j) p.o[j] = f2bf(acc[j] + bias);
        st_sc8(&xp1t[g2 * 196608 + (size_t)(t & 3) * 49152 + n_g * 16 + hi4 * 4], p.q);
        signal_flag(&X[g2 * 768 + wgx * 32], t + 1);
      }
    }
  } else if (wg < 64) {
    // ================= gang1 zr (layer1) =================
    const int wgl = wg - 48;             // 0..15
    const int gw = wgl * 8 + wv;         // 0..127
    const int n_g = gw * 16 + col;       // 0..2047
    const bool is_z = (wgl < 8);
    const int rc = n_g - 1024;
    u32x4 Bf[32];
    load_Bf(Bf, Whb + (size_t)3072 * 1024, n_g, hi4);
    for (int s = 0; s < 512; ++s) {
#pragma unroll
      for (int g2 = 0; g2 < 2; ++g2) {
        wait_flags2(X + g2 * 768, 24, s + 1, B1 + g2 * 256, 8, s, tid);
        u32x2 xq = ld_sc8(&xp1t[g2 * 196608 + (size_t)(s & 3) * 49152 + n_g * 16 + hi4 * 4]);
        u32x4 v[4];
        stage_issue16(h1ring + g2 * 65536 + (size_t)((s - 1) & 3) * 16384, v, tid);
        wait_vm0();
        stage_write16(smem, v, tid);
        __syncthreads();
        float xpv[4];
        {
          union { u32x2 q; u16 o[4]; } xx; xx.q = xq;
#pragma unroll
          for (int j = 0; j < 4; ++j) xpv[j] = bf2f(xx.o[j]);
        }
        f32x4 acc = {0.f, 0.f, 0.f, 0.f};
#pragma unroll
        for (int kt = 0; kt < 32; ++kt)
          acc = MFMA16(as_bf(read_frag_sw(smem, col, kt, hi4)), as_bf(Bf[kt]), acc);
        if (is_z) {
          union { float f[4]; u32x4 q; } q0;
#pragma unroll
          for (int j = 0; j < 4; ++j) q0.f[j] = sigmoidf_(xpv[j] + acc[j]);
          st_sc16(&z1_t[g2 * 16384 + n_g * 16 + hi4 * 4], q0.q);
        } else {
          u16 rhv[4];
#pragma unroll
          for (int j = 0; j < 4; ++j) {
            int bl = hi4 * 4 + j;
            float rv = sigmoidf_(xpv[j] + acc[j]);
            u16 hraw = smem[bl * 1024 + ((((rc >> 3) ^ (bl & 7)) << 3) | (rc & 7))];
            rhv[j] = f2bf(rv * bf2f(hraw));
          }
          store_tile_wide(smem, wv, col, hi4, rhv,
                          rh1 + g2 * 16384, gw * 16 - 1024, lane);
        }
        signal_flag(&A1[g2 * 512 + wgl * 32], s + 1);
      }
    }
  } else if (wg < 72) {
    // ================= gang1 g (layer1) =================
    const int wgl = wg - 64;             // 0..7
    const int gw = 128 + wgl * 8 + wv;   // 128..191
    const int n_g = gw * 16 + col;       // 2048..3071
    const int gc = n_g - 2048;
    u32x4 Bf[32];
    load_Bf(Bf, Whb + (size_t)3072 * 1024, n_g, hi4);
    float h_reg[2][4];
#pragma unroll
    for (int g2 = 0; g2 < 2; ++g2)
#pragma unroll
      for (int j = 0; j < 4; ++j)
        h_reg[g2][j] = h0in[(g2 * 16 + hi4 * 4 + j) * 2048 + 1024 + gc];
    for (int s = 0; s < 512; ++s) {
#pragma unroll
      for (int g2 = 0; g2 < 2; ++g2) {
        // A1 same-step; Y ring guard (slot s&3 consumed by ygang through s-4)
        wait_flags2(A1 + g2 * 512, 16, s + 1, Y + g2 * 256, 8, s - 3, tid);
        u32x2 xq = ld_sc8(&xp1t[g2 * 196608 + (size_t)(s & 3) * 49152 + n_g * 16 + hi4 * 4]);
        u32x4 v[4];
        stage_issue16(rh1 + g2 * 16384, v, tid);
        u32x4 zq = ld_sc16(&z1_t[g2 * 16384 + gc * 16 + hi4 * 4]);
        wait_vm0();
        stage_write16(smem, v, tid);
        __syncthreads();
        float xpv[4];
        {
          union { u32x2 q; u16 o[4]; } xx; xx.q = xq;
#pragma unroll
          for (int j = 0; j < 4; ++j) xpv[j] = bf2f(xx.o[j]);
        }
        f32x4 acc = {0.f, 0.f, 0.f, 0.f};
#pragma unroll
        for (int kt = 0; kt < 32; ++kt)
          acc = MFMA16(as_bf(read_frag_sw(smem, col, kt, hi4)), as_bf(Bf[kt]), acc);
        union { u32x4 q; float f[4]; } zz; zz.q = zq;
        u16 hv[4];
#pragma unroll
        for (int j = 0; j < 4; ++j) {
          float gv = sigmoidf_(xpv[j] + acc[j]);
          float hn = zz.f[j] * h_reg[g2][j] + (1.0f - zz.f[j]) * gv;
          h_reg[g2][j] = hn;
          hv[j] = f2bf(hn);
        }
        store_tile_wide(smem, wv, col, hi4, hv,
                        h1ring + g2 * 65536 + (size_t)(s & 3) * 16384,
                        gw * 16 - 2048, lane);
        signal_flag(&B1[g2 * 256 + wgl * 32], s + 1);
        if (s == 511) {
#pragma unroll
          for (int j = 0; j < 4; ++j)
            hidden[(g2 * 16 + hi4 * 4 + j) * 2048 + 1024 + gc] = h_reg[g2][j];
        }
      }
    }
  } else {
    // ================= ygang: out(s) = h1(s) @ Why^T + bhy =================
    const int wgy = wg - 72;             // 0..7
    const int gw = wgy * 8 + wv;         // 0..63
    const int n_g = gw * 16 + col;       // 0..1023
    u32x4 Bf[32];
    load_Bf(Bf, Why, n_g, hi4);
    const float bias = bhy[n_g];
    for (int s = 0; s < 512; ++s) {
#pragma unroll
      for (int g2 = 0; g2 < 2; ++g2) {
        wait_flags(B1 + g2 * 256, 8, s + 1, tid);  // h1(s) in ring slot s&3
        u32x4 v[4];
        stage_issue16(h1ring + g2 * 65536 + (size_t)(s & 3) * 16384, v, tid);
        wait_vm0();
        stage_write16(smem, v, tid);
        __syncthreads();
        f32x4 acc = {0.f, 0.f, 0.f, 0.f};
#pragma unroll
        for (int kt = 0; kt < 32; ++kt)
          acc = MFMA16(as_bf(read_frag_sw(smem, col, kt, hi4)), as_bf(Bf[kt]), acc);
        // cached f32 stores (consumed after kernel end)
#pragma unroll
        for (int j = 0; j < 4; ++j) {
          int b = g2 * 16 + hi4 * 4 + j;
          outp[(size_t)b * (512 * 1024) + (size_t)s * 1024 + n_g] = acc[j] + bias;
        }
        signal_flag(&Y[g2 * 256 + wgy * 32], s + 1);
      }
    }
  }
}

// ---------------- 128x128-tile bf16 GEMM: C[m,n] = sum_k A[m,k]*W[n,k] + bias[n] ----------------
// bf16 out to xproj layout [s][b][3072] with m = b*512+s
__global__ __launch_bounds__(256, 1) void gemm_bt_kernel(
    const u16* __restrict__ A, const u16* __restrict__ W,
    const float* __restrict__ bias, u16* __restrict__ out,
    int M, int N, int K)
{
  __shared__ u16 At[128 * 32];
  __shared__ u16 Wt[128 * 32];
  const int tid = threadIdx.x;
  const int lane = tid & 63, wv = tid >> 6;
  const int wr = wv >> 1, wc = wv & 1;
  const int m0 = (int)blockIdx.y * 128, n0 = (int)blockIdx.x * 128;
  const int col = lane & 15, hi4 = lane >> 4;
  const size_t K2 = (size_t)K * 2;

  f32x4 acc[4][4];
#pragma unroll
  for (int i = 0; i < 4; ++i)
#pragma unroll
    for (int j = 0; j < 4; ++j) acc[i][j] = (f32x4){0.f, 0.f, 0.f, 0.f};

  const int nkt = K >> 5;
  for (int kt = 0; kt < nkt; ++kt) {
    __syncthreads();
#pragma unroll
    for (int it = 0; it < 2; ++it) {
      int cb = wv * 128 + it * 64;
      int ub = __builtin_amdgcn_readfirstlane(cb);
      int c = cb + lane;
      int row = c >> 2, slot = c & 3;
      int koff = (slot ^ ((row >> 1) & 3)) * 16;
      gll16((const char*)A + (size_t)(m0 + row) * K2 + (size_t)kt * 64 + koff,
            (char*)At + (size_t)ub * 16);
      gll16((const char*)W + (size_t)(n0 + row) * K2 + (size_t)kt * 64 + koff,
            (char*)Wt + (size_t)ub * 16);
    }
    __syncthreads();
    u32x4 Af[4], Wf[4];
#pragma unroll
    for (int i = 0; i < 4; ++i) {
      int row = wr * 64 + i * 16 + col;
      int sc = hi4 ^ ((row >> 1) & 3);
      Af[i] = *(const u32x4*)((const char*)At + (size_t)row * 64 + (size_t)sc * 16);
    }
#pragma unroll
    for (int j = 0; j < 4; ++j) {
      int row = wc * 64 + j * 16 + col;
      int sc = hi4 ^ ((row >> 1) & 3);
      Wf[j] = *(const u32x4*)((const char*)Wt + (size_t)row * 64 + (size_t)sc * 16);
    }
#pragma unroll
    for (int i = 0; i < 4; ++i)
#pragma unroll
      for (int j = 0; j < 4; ++j)
        acc[i][j] = MFMA16(as_bf(Af[i]), as_bf(Wf[j]), acc[i][j]);
  }
#pragma unroll
  for (int i = 0; i < 4; ++i) {
#pragma unroll
    for (int j = 0; j < 4; ++j) {
      int n = n0 + wc * 64 + j * 16 + col;
      float bv = bias[n];
#pragma unroll
      for (int jj = 0; jj < 4; ++jj) {
        int m = m0 + wr * 64 + i * 16 + hi4 * 4 + jj;
        float v = acc[i][j][jj] + bv;
        out[(size_t)(m & 511) * (32 * 3072) + (size_t)(m >> 9) * 3072 + n] = f2bf(v);
      }
    }
  }
}

// ---------------- converters (single launch, 4 regions) ----------------
__global__ void cvt_all_kernel(const float* __restrict__ x, u16* __restrict__ xbf,
                               const float* __restrict__ Wx, u16* __restrict__ Wxb,
                               const float* __restrict__ Wh, u16* __restrict__ Whb,
                               const float* __restrict__ Why, u16* __restrict__ Whyb) {
  int wg = (int)blockIdx.x;
  const float* src; u16* dst; int base;
  if (wg < 8192)       { src = x;   dst = xbf;  base = wg; }
  else if (wg < 11264) { src = Wx;  dst = Wxb;  base = wg - 8192; }
  else if (wg < 14336) { src = Wh;  dst = Whb;  base = wg - 11264; }
  else                 { src = Why; dst = Whyb; base = wg - 14336; }
  int i = (base * 256 + (int)threadIdx.x) * 8;  // exact multiples, no tails
  float4 a = *(const float4*)(src + i);
  float4 b = *(const float4*)(src + i + 4);
  union { u16 o[8]; u32x4 q; } u;
  u.o[0] = f2bf(a.x); u.o[1] = f2bf(a.y); u.o[2] = f2bf(a.z); u.o[3] = f2bf(a.w);
  u.o[4] = f2bf(b.x); u.o[5] = f2bf(b.y); u.o[6] = f2bf(b.z); u.o[7] = f2bf(b.w);
  *(u32x4*)(dst + i) = u.q;
}

// h0 init: layer0 -> h0ring slot 3 (per group), layer1 -> h1ring slot 3 (per group)
__global__ void h0cvt_kernel(const float* __restrict__ h0, u16* __restrict__ h0ring,
                             u16* __restrict__ h1ring) {
  int i = (int)blockIdx.x * 256 + (int)threadIdx.x;  // 0..32767
  if (i < 32768) {
    int b = i >> 10, j = i & 1023;
    int g2 = b >> 4, bl = b & 15;
    h0ring[g2 * 65536 + 3 * 16384 + bl * 1024 + j] = f2bf(h0[b * 2048 + j]);
    h1ring[g2 * 65536 + 3 * 16384 + bl * 1024 + j] = f2bf(h0[b * 2048 + 1024 + j]);
  }
}

// ---------------- host ----------------
extern "C" void kernel_launch(void* const* d_in, const int* in_sizes, int n_in,
                              void* d_out, int out_size, void* d_ws, size_t ws_size,
                              hipStream_t stream) {
  const float* x   = (const float*)d_in[0];
  const float* h0  = (const float*)d_in[1];
  const float* Wx  = (const float*)d_in[2];
  const float* bx  = (const float*)d_in[3];
  const float* Wh  = (const float*)d_in[4];
  const float* Why = (const float*)d_in[5];
  const float* bhy = (const float*)d_in[6];
  float* out = (float*)d_out;
  float* hidden = out + (size_t)32 * 512 * 1024;

  char* ws = (char*)d_ws;
  u16* xproj  = (u16*)ws;  ws += (size_t)512 * 32 * 3072 * 2;   // 100.7 MB
  u16* xbf    = (u16*)ws;  ws += (size_t)32 * 512 * 1024 * 2;   // 33.6 MB
  u16* Wxb    = (u16*)ws;  ws += (size_t)2 * 3072 * 1024 * 2;   // 12.6 MB
  u16* Whb    = (u16*)ws;  ws += (size_t)2 * 3072 * 1024 * 2;   // 12.6 MB
  u16* Whyb   = (u16*)ws;  ws += (size_t)1024 * 1024 * 2;       // 2.1 MB
  u16* h0ring = (u16*)ws;  ws += 2 * 4 * 16384 * 2;             // 256 KB
  u16* h1ring = (u16*)ws;  ws += 2 * 4 * 16384 * 2;             // 256 KB
  u16* rh0    = (u16*)ws;  ws += 2 * 16384 * 2;
  u16* rh1    = (u16*)ws;  ws += 2 * 16384 * 2;
  float* z0_t = (float*)ws; ws += 2 * 16384 * 4;                // 128 KB
  float* z1_t = (float*)ws; ws += 2 * 16384 * 4;
  u16* xp1t   = (u16*)ws;  ws += (size_t)2 * 4 * 3072 * 16 * 2; // 768 KB
  int* bar    = (int*)ws;  ws += 32768;

  // all f32->bf16 conversions in one launch (exact sizes, no tails)
  cvt_all_kernel<<<14848, 256, 0, stream>>>(x, xbf, Wx, Wxb, Wh, Whb, Why, Whyb);

  // layer0 x-projection (big GEMM)
  gemm_bt_kernel<<<dim3(3072 / 128, 16384 / 128), 256, 0, stream>>>(
      xbf, Wxb, bx, xproj, 16384, 3072, 1024);
  (void)hipMemsetAsync(bar, 0, 32768, stream);
  h0cvt_kernel<<<128, 256, 0, stream>>>(h0, h0ring, h1ring);

  // pipelined recurrence: layer0 + layer1-xproj + layer1 + output projection
  gru_pipe_kernel<<<80, 512, 0, stream>>>(
      xproj, Whb, Wxb + (size_t)3072 * 1024, bx, h0,
      h0ring, h1ring, rh0, rh1, z0_t, z1_t, xp1t,
      Whyb, bhy, out, hidden, bar);
}

// Round 14
// 3632.412 us; speedup vs baseline: 1.0466x; 1.0466x over previous
//
#include <hip/hip_runtime.h>
#include <stdint.h>

// B=32, S=512, I=H=O=1024, L=2.  Pipeline: gang0 -> xgang -> gang1 -> ygang,
// batch-halves G0/G1 interleaved.  (R12 structure; R13's wide-store transpose
// reverted — ack is RTT-latency-bound, not store-count-bound.)

typedef __bf16 bf16x8 __attribute__((ext_vector_type(8)));
typedef float f32x4 __attribute__((ext_vector_type(4)));
typedef unsigned short u16;
typedef unsigned int u32;
typedef u32 u32x2 __attribute__((ext_vector_type(2)));
typedef u32 u32x4 __attribute__((ext_vector_type(4)));

typedef __attribute__((address_space(1))) u32 as1_u32;
typedef __attribute__((address_space(3))) u32 as3_u32;

__device__ __forceinline__ u16 f2bf(float f) {
  union { float f; u32 u; } a; a.f = f;
  u32 u = a.u;
  u32 r = (u + 0x7fffu + ((u >> 16) & 1u)) >> 16;  // RNE
  return (u16)r;
}
__device__ __forceinline__ float bf2f(u16 b) {
  union { u32 u; float f; } a; a.u = ((u32)b) << 16;
  return a.f;
}
__device__ __forceinline__ float sigmoidf_(float x) {
  return 1.0f / (1.0f + __expf(-x));
}
__device__ __forceinline__ bf16x8 as_bf(u32x4 q) {
  union { u32x4 q; bf16x8 v; } u; u.q = q; return u.v;
}

#define MFMA16(a, b, c) __builtin_amdgcn_mfma_f32_16x16x32_bf16((a), (b), (c), 0, 0, 0)

// async global->LDS, 16B per lane (GEMM staging only; cached path)
__device__ __forceinline__ void gll16(const void* g, void* l) {
  __builtin_amdgcn_global_load_lds((as1_u32*)g, (as3_u32*)l, 16, 0, 0);
}

// ---------------- sc0sc1 (L3-coherent, cross-XCD) memory ops — proven ----------------
__device__ __forceinline__ u32x4 ld_sc16(const void* p) {
  u32x4 r;
  asm volatile("global_load_dwordx4 %0, %1, off sc0 sc1" : "=v"(r) : "v"(p) : "memory");
  return r;
}
__device__ __forceinline__ u32x2 ld_sc8(const void* p) {
  u32x2 r;
  asm volatile("global_load_dwordx2 %0, %1, off sc0 sc1" : "=v"(r) : "v"(p) : "memory");
  return r;
}
__device__ __forceinline__ void st_sc2(void* p, u16 v) {
  u32 w = v;
  asm volatile("global_store_short %0, %1, off sc0 sc1" :: "v"(p), "v"(w) : "memory");
}
__device__ __forceinline__ void st_sc8(void* p, u32x2 v) {
  asm volatile("global_store_dwordx2 %0, %1, off sc0 sc1" :: "v"(p), "v"(v) : "memory");
}
__device__ __forceinline__ void st_sc16(void* p, u32x4 v) {
  asm volatile("global_store_dwordx4 %0, %1, off sc0 sc1" :: "v"(p), "v"(v) : "memory");
}
__device__ __forceinline__ void wait_vm0() {
  asm volatile("s_waitcnt vmcnt(0)" ::: "memory");
  __builtin_amdgcn_sched_barrier(0);  // rule #18
}
__device__ __forceinline__ int ldflag(const int* p) {
  int r;
  asm volatile("global_load_dword %0, %1, off sc0 sc1\n\ts_waitcnt vmcnt(0)"
               : "=v"(r) : "v"(p) : "memory");
  return r;
}
__device__ __forceinline__ void stflag(int* p, int v) {
  asm volatile("global_store_dword %0, %1, off sc0 sc1" :: "v"(p), "v"(v) : "memory");
}

// ---------------- flag sync: monotonic counters, one 128B line per flag ----------------
__device__ __forceinline__ void signal_flag(int* flag, int val) {
  asm volatile("s_waitcnt vmcnt(0)" ::: "memory");  // our sc stores acked at L3
  __syncthreads();                                  // all waves done
  if (threadIdx.x == 0) stflag(flag, val);
}
__device__ __forceinline__ void wait_flags(int* flags, int nf, int target, int tid) {
  if (tid < 64) {
    for (;;) {
      int v = (tid < nf) ? ldflag(flags + tid * 32) : target;
      if (__all(v >= target)) break;
      __builtin_amdgcn_s_sleep(1);
    }
  }
  __syncthreads();
}
// two flag groups, independent targets (t<=0 auto-satisfied; flags start at 0)
__device__ __forceinline__ void wait_flags2(int* f1, int n1, int t1,
                                            int* f2, int n2, int t2, int tid) {
  if (tid < 64) {
    const int* addr = nullptr;
    int tgt = 0, active = 0;
    if (tid < n1) { addr = f1 + tid * 32; tgt = t1; active = 1; }
    else if (tid < n1 + n2) { addr = f2 + (tid - n1) * 32; tgt = t2; active = 1; }
    for (;;) {
      int v = active ? ldflag(addr) : 0;
      int sat = (!active) || (v >= tgt);
      if (__all(sat)) break;
      __builtin_amdgcn_s_sleep(1);
    }
  }
  __syncthreads();
}

// Stage a [16][1024] bf16 matrix (32 KB) global->LDS, sc-coherent, reg-staged.
// LDS chunk (row, sc) <- global chunk (row, sc ^ (row&7))  (16B chunks).
__device__ __forceinline__ void stage_issue16(const u16* g, u32x4* v, int tid) {
#pragma unroll
  for (int it = 0; it < 4; ++it) {
    int cc = tid + it * 512;          // 16B-chunk id 0..2047
    int row = cc >> 7, sc = cc & 127;
    int gsc = sc ^ (row & 7);
    v[it] = ld_sc16((const char*)g + (size_t)(row * 128 + gsc) * 16);
  }
}
__device__ __forceinline__ void stage_write16(u16* lds, const u32x4* v, int tid) {
#pragma unroll
  for (int it = 0; it < 4; ++it) {
    int cc = tid + it * 512;
    *(u32x4*)((char*)lds + (size_t)cc * 16) = v[it];
  }
}
__device__ __forceinline__ u32x4 read_frag_sw(const u16* lds, int row, int kt, int hi4) {
  int cc = kt * 4 + hi4;
  int sc = cc ^ (row & 7);
  return *(const u32x4*)((const char*)lds + (size_t)row * 2048 + (size_t)sc * 16);
}

// xpv: cached strided loads from xproj [512][32][3072]
__device__ __forceinline__ void load_xpv4(float* xpv, const u16* xproj, int s,
                                          int n_g, int b0) {
  const u16* xb = xproj + (size_t)s * (32 * 3072) + (size_t)b0 * 3072 + n_g;
#pragma unroll
  for (int j = 0; j < 4; ++j) xpv[j] = bf2f(xb[(size_t)j * 3072]);
}

// load persistent weight fragments: row n_g of W (row-major [.][1024] bf16)
__device__ __forceinline__ void load_Bf(u32x4* Bf, const u16* W, int n_g, int hi4) {
  const u16* wrow = W + (size_t)n_g * 1024 + 8 * hi4;
#pragma unroll
  for (int kt = 0; kt < 32; ++kt) Bf[kt] = *(const u32x4*)(wrow + kt * 32);
}

// ---------------- pipelined GRU kernel (both layers + x-proj + out-proj) ----------------
// grid = 80 wgs x 512 thr:
//   wg  0..15 : gang0 zr (z:0..7, r:8..15)  layer0
//   wg 16..23 : gang0 g                      layer0; writes h0ring
//   wg 24..47 : xgang (xp1 = h0 @ Wx1^T+bx1)
//   wg 48..63 : gang1 zr                     layer1
//   wg 64..71 : gang1 g                      layer1; writes h1ring/hidden
//   wg 72..79 : ygang (out = h1 @ Why^T+bhy) -> d_out (cached f32)
// Per-group flag regions (128B-padded ints):
//   A0 = bar + g*512 (16) | B0 = bar+1024+g*256 (8) | A1 = bar+1536+g*512 (16)
//   B1 = bar+2560+g*256 (8) | X = bar+3072+g*768 (24) | Y = bar+4608+g*256 (8)
__global__ __launch_bounds__(512, 1) void gru_pipe_kernel(
    const u16* __restrict__ xproj,   // [512][32][3072] layer0 x-projection
    const u16* __restrict__ Whb,     // [2][3072][1024]
    const u16* __restrict__ Wx1,     // [3072][1024] (layer1)
    const float* __restrict__ bx,    // [2][3072]
    const float* __restrict__ h0in,  // [32][2][1024]
    u16* __restrict__ h0ring,        // [2][4][16][1024]
    u16* __restrict__ h1ring,        // [2][4][16][1024]
    u16* __restrict__ rh0,           // [2][16][1024]
    u16* __restrict__ rh1,           // [2][16][1024]
    float* __restrict__ z0_t,        // [2][1024][16]
    float* __restrict__ z1_t,        // [2][1024][16]
    u16* __restrict__ xp1t,          // [2][4][3072][16]
    const u16* __restrict__ Why,     // [1024][1024] bf16
    const float* __restrict__ bhy,   // [1024]
    float* __restrict__ outp,        // [32][512][1024] f32 (d_out head)
    float* __restrict__ hidden,      // [32][2][1024] (d_out tail)
    int* __restrict__ bar)
{
  __shared__ u16 smem[16 * 1024];  // 32 KB staging
  const int tid = (int)threadIdx.x;
  const int lane = tid & 63;
  const int wv = tid >> 6;
  const int wg = (int)blockIdx.x;
  const int col = lane & 15;
  const int hi4 = lane >> 4;

  int* A0 = bar;
  int* B0 = bar + 1024;
  int* A1 = bar + 1536;
  int* B1 = bar + 2560;
  int* X  = bar + 3072;
  int* Y  = bar + 4608;

  if (wg < 16) {
    // ================= gang0 zr (layer0) =================
    const int gw = wg * 8 + wv;          // 0..127
    const int n_g = gw * 16 + col;       // 0..2047
    const bool is_z = (wg < 8);
    const int rc = n_g - 1024;
    u32x4 Bf[32];
    load_Bf(Bf, Whb, n_g, hi4);
    for (int s = 0; s < 512; ++s) {
#pragma unroll
      for (int g2 = 0; g2 < 2; ++g2) {
        float xpv[4];
        load_xpv4(xpv, xproj, s, n_g, g2 * 16 + hi4 * 4);
        wait_flags(B0 + g2 * 256, 8, s, tid);  // h_g(s-1) stored
        u32x4 v[4];
        stage_issue16(h0ring + g2 * 65536 + (size_t)((s - 1) & 3) * 16384, v, tid);
        wait_vm0();
        stage_write16(smem, v, tid);
        __syncthreads();
        f32x4 acc = {0.f, 0.f, 0.f, 0.f};
#pragma unroll
        for (int kt = 0; kt < 32; ++kt)
          acc = MFMA16(as_bf(read_frag_sw(smem, col, kt, hi4)), as_bf(Bf[kt]), acc);
        if (is_z) {
          union { float f[4]; u32x4 q; } q0;
#pragma unroll
          for (int j = 0; j < 4; ++j) q0.f[j] = sigmoidf_(xpv[j] + acc[j]);
          st_sc16(&z0_t[g2 * 16384 + n_g * 16 + hi4 * 4], q0.q);
        } else {
#pragma unroll
          for (int j = 0; j < 4; ++j) {
            int bl = hi4 * 4 + j;
            float rv = sigmoidf_(xpv[j] + acc[j]);
            u16 hraw = smem[bl * 1024 + ((((rc >> 3) ^ (bl & 7)) << 3) | (rc & 7))];
            st_sc2(&rh0[g2 * 16384 + bl * 1024 + rc], f2bf(rv * bf2f(hraw)));
          }
        }
        signal_flag(&A0[g2 * 512 + wg * 32], s + 1);
      }
    }
  } else if (wg < 24) {
    // ================= gang0 g (layer0) =================
    const int wgl = wg - 16;             // 0..7
    const int gw = 128 + wgl * 8 + wv;   // 128..191
    const int n_g = gw * 16 + col;       // 2048..3071
    const int gc = n_g - 2048;
    u32x4 Bf[32];
    load_Bf(Bf, Whb, n_g, hi4);
    float h_reg[2][4];
#pragma unroll
    for (int g2 = 0; g2 < 2; ++g2)
#pragma unroll
      for (int j = 0; j < 4; ++j)
        h_reg[g2][j] = h0in[(g2 * 16 + hi4 * 4 + j) * 2048 + gc];
    for (int s = 0; s < 512; ++s) {
#pragma unroll
      for (int g2 = 0; g2 < 2; ++g2) {
        float xpv[4];
        load_xpv4(xpv, xproj, s, n_g, g2 * 16 + hi4 * 4);
        wait_flags2(A0 + g2 * 512, 16, s + 1, X + g2 * 768, 24, s - 3, tid);
        u32x4 v[4];
        stage_issue16(rh0 + g2 * 16384, v, tid);
        u32x4 zq = ld_sc16(&z0_t[g2 * 16384 + gc * 16 + hi4 * 4]);
        wait_vm0();
        stage_write16(smem, v, tid);
        __syncthreads();
        f32x4 acc = {0.f, 0.f, 0.f, 0.f};
#pragma unroll
        for (int kt = 0; kt < 32; ++kt)
          acc = MFMA16(as_bf(read_frag_sw(smem, col, kt, hi4)), as_bf(Bf[kt]), acc);
        union { u32x4 q; float f[4]; } zz; zz.q = zq;
        u16* hslot = h0ring + g2 * 65536 + (size_t)(s & 3) * 16384;
#pragma unroll
        for (int j = 0; j < 4; ++j) {
          int bl = hi4 * 4 + j;
          float gv = sigmoidf_(xpv[j] + acc[j]);
          float hn = zz.f[j] * h_reg[g2][j] + (1.0f - zz.f[j]) * gv;
          h_reg[g2][j] = hn;
          st_sc2(&hslot[bl * 1024 + gc], f2bf(hn));
        }
        signal_flag(&B0[g2 * 256 + wgl * 32], s + 1);
        if (s == 511) {
#pragma unroll
          for (int j = 0; j < 4; ++j)
            hidden[(g2 * 16 + hi4 * 4 + j) * 2048 + gc] = h_reg[g2][j];
        }
      }
    }
  } else if (wg < 48) {
    // ================= xgang: xp1(t) = h0(t) @ Wx1^T + bx1 =================
    const int wgx = wg - 24;             // 0..23
    const int gw = wgx * 8 + wv;         // 0..191
    const int n_g = gw * 16 + col;       // 0..3071
    u32x4 Bf[32];
    load_Bf(Bf, Wx1, n_g, hi4);
    const float bias = bx[3072 + n_g];
    for (int t = 0; t < 512; ++t) {
#pragma unroll
      for (int g2 = 0; g2 < 2; ++g2) {
        wait_flags2(B0 + g2 * 256, 8, t + 1, B1 + g2 * 256, 8, t - 3, tid);
        u32x4 v[4];
        stage_issue16(h0ring + g2 * 65536 + (size_t)(t & 3) * 16384, v, tid);
        wait_vm0();
        stage_write16(smem, v, tid);
        __syncthreads();
        f32x4 acc = {0.f, 0.f, 0.f, 0.f};
#pragma unroll
        for (int kt = 0; kt < 32; ++kt)
          acc = MFMA16(as_bf(read_frag_sw(smem, col, kt, hi4)), as_bf(Bf[kt]), acc);
        union { u16 o[4]; u32x2 q; } p;
#pragma unroll
        for (int j = 0; j < 4; ++j) p.o[j] = f2bf(acc[j] + bias);
        st_sc8(&xp1t[g2 * 196608 + (size_t)(t & 3) * 49152 + n_g * 16 + hi4 * 4], p.q);
        signal_flag(&X[g2 * 768 + wgx * 32], t + 1);
      }
    }
  } else if (wg < 64) {
    // ================= gang1 zr (layer1) =================
    const int wgl = wg - 48;             // 0..15
    const int gw = wgl * 8 + wv;         // 0..127
    const int n_g = gw * 16 + col;       // 0..2047
    const bool is_z = (wgl < 8);
    const int rc = n_g - 1024;
    u32x4 Bf[32];
    load_Bf(Bf, Whb + (size_t)3072 * 1024, n_g, hi4);
    for (int s = 0; s < 512; ++s) {
#pragma unroll
      for (int g2 = 0; g2 < 2; ++g2) {
        wait_flags2(X + g2 * 768, 24, s + 1, B1 + g2 * 256, 8, s, tid);
        u32x2 xq = ld_sc8(&xp1t[g2 * 196608 + (size_t)(s & 3) * 49152 + n_g * 16 + hi4 * 4]);
        u32x4 v[4];
        stage_issue16(h1ring + g2 * 65536 + (size_t)((s - 1) & 3) * 16384, v, tid);
        wait_vm0();
        stage_write16(smem, v, tid);
        __syncthreads();
        float xpv[4];
        {
          union { u32x2 q; u16 o[4]; } xx; xx.q = xq;
#pragma unroll
          for (int j = 0; j < 4; ++j) xpv[j] = bf2f(xx.o[j]);
        }
        f32x4 acc = {0.f, 0.f, 0.f, 0.f};
#pragma unroll
        for (int kt = 0; kt < 32; ++kt)
          acc = MFMA16(as_bf(read_frag_sw(smem, col, kt, hi4)), as_bf(Bf[kt]), acc);
        if (is_z) {
          union { float f[4]; u32x4 q; } q0;
#pragma unroll
          for (int j = 0; j < 4; ++j) q0.f[j] = sigmoidf_(xpv[j] + acc[j]);
          st_sc16(&z1_t[g2 * 16384 + n_g * 16 + hi4 * 4], q0.q);
        } else {
#pragma unroll
          for (int j = 0; j < 4; ++j) {
            int bl = hi4 * 4 + j;
            float rv = sigmoidf_(xpv[j] + acc[j]);
            u16 hraw = smem[bl * 1024 + ((((rc >> 3) ^ (bl & 7)) << 3) | (rc & 7))];
            st_sc2(&rh1[g2 * 16384 + bl * 1024 + rc], f2bf(rv * bf2f(hraw)));
          }
        }
        signal_flag(&A1[g2 * 512 + wgl * 32], s + 1);
      }
    }
  } else if (wg < 72) {
    // ================= gang1 g (layer1) =================
    const int wgl = wg - 64;             // 0..7
    const int gw = 128 + wgl * 8 + wv;   // 128..191
    const int n_g = gw * 16 + col;       // 2048..3071
    const int gc = n_g - 2048;
    u32x4 Bf[32];
    load_Bf(Bf, Whb + (size_t)3072 * 1024, n_g, hi4);
    float h_reg[2][4];
#pragma unroll
    for (int g2 = 0; g2 < 2; ++g2)
#pragma unroll
      for (int j = 0; j < 4; ++j)
        h_reg[g2][j] = h0in[(g2 * 16 + hi4 * 4 + j) * 2048 + 1024 + gc];
    for (int s = 0; s < 512; ++s) {
#pragma unroll
      for (int g2 = 0; g2 < 2; ++g2) {
        // A1 same-step; Y ring guard (slot s&3 consumed by ygang through s-4)
        wait_flags2(A1 + g2 * 512, 16, s + 1, Y + g2 * 256, 8, s - 3, tid);
        u32x2 xq = ld_sc8(&xp1t[g2 * 196608 + (size_t)(s & 3) * 49152 + n_g * 16 + hi4 * 4]);
        u32x4 v[4];
        stage_issue16(rh1 + g2 * 16384, v, tid);
        u32x4 zq = ld_sc16(&z1_t[g2 * 16384 + gc * 16 + hi4 * 4]);
        wait_vm0();
        stage_write16(smem, v, tid);
        __syncthreads();
        float xpv[4];
        {
          union { u32x2 q; u16 o[4]; } xx; xx.q = xq;
#pragma unroll
          for (int j = 0; j < 4; ++j) xpv[j] = bf2f(xx.o[j]);
        }
        f32x4 acc = {0.f, 0.f, 0.f, 0.f};
#pragma unroll
        for (int kt = 0; kt < 32; ++kt)
          acc = MFMA16(as_bf(read_frag_sw(smem, col, kt, hi4)), as_bf(Bf[kt]), acc);
        union { u32x4 q; float f[4]; } zz; zz.q = zq;
        u16* hslot = h1ring + g2 * 65536 + (size_t)(s & 3) * 16384;
#pragma unroll
        for (int j = 0; j < 4; ++j) {
          int bl = hi4 * 4 + j;
          float gv = sigmoidf_(xpv[j] + acc[j]);
          float hn = zz.f[j] * h_reg[g2][j] + (1.0f - zz.f[j]) * gv;
          h_reg[g2][j] = hn;
          st_sc2(&hslot[bl * 1024 + gc], f2bf(hn));
        }
        signal_flag(&B1[g2 * 256 + wgl * 32], s + 1);
        if (s == 511) {
#pragma unroll
          for (int j = 0; j < 4; ++j)
            hidden[(g2 * 16 + hi4 * 4 + j) * 2048 + 1024 + gc] = h_reg[g2][j];
        }
      }
    }
  } else {
    // ================= ygang: out(s) = h1(s) @ Why^T + bhy =================
    const int wgy = wg - 72;             // 0..7
    const int gw = wgy * 8 + wv;         // 0..63
    const int n_g = gw * 16 + col;       // 0..1023
    u32x4 Bf[32];
    load_Bf(Bf, Why, n_g, hi4);
    const float bias = bhy[n_g];
    for (int s = 0; s < 512; ++s) {
#pragma unroll
      for (int g2 = 0; g2 < 2; ++g2) {
        wait_flags(B1 + g2 * 256, 8, s + 1, tid);  // h1(s) in ring slot s&3
        u32x4 v[4];
        stage_issue16(h1ring + g2 * 65536 + (size_t)(s & 3) * 16384, v, tid);
        wait_vm0();
        stage_write16(smem, v, tid);
        __syncthreads();
        f32x4 acc = {0.f, 0.f, 0.f, 0.f};
#pragma unroll
        for (int kt = 0; kt < 32; ++kt)
          acc = MFMA16(as_bf(read_frag_sw(smem, col, kt, hi4)), as_bf(Bf[kt]), acc);
        // cached f32 stores (consumed after kernel end)
#pragma unroll
        for (int j = 0; j < 4; ++j) {
          int b = g2 * 16 + hi4 * 4 + j;
          outp[(size_t)b * (512 * 1024) + (size_t)s * 1024 + n_g] = acc[j] + bias;
        }
        signal_flag(&Y[g2 * 256 + wgy * 32], s + 1);
      }
    }
  }
}

// ---------------- 128x128-tile bf16 GEMM: C[m,n] = sum_k A[m,k]*W[n,k] + bias[n] ----------------
// bf16 out to xproj layout [s][b][3072] with m = b*512+s
__global__ __launch_bounds__(256, 1) void gemm_bt_kernel(
    const u16* __restrict__ A, const u16* __restrict__ W,
    const float* __restrict__ bias, u16* __restrict__ out,
    int M, int N, int K)
{
  __shared__ u16 At[128 * 32];
  __shared__ u16 Wt[128 * 32];
  const int tid = threadIdx.x;
  const int lane = tid & 63, wv = tid >> 6;
  const int wr = wv >> 1, wc = wv & 1;
  const int m0 = (int)blockIdx.y * 128, n0 = (int)blockIdx.x * 128;
  const int col = lane & 15, hi4 = lane >> 4;
  const size_t K2 = (size_t)K * 2;

  f32x4 acc[4][4];
#pragma unroll
  for (int i = 0; i < 4; ++i)
#pragma unroll
    for (int j = 0; j < 4; ++j) acc[i][j] = (f32x4){0.f, 0.f, 0.f, 0.f};

  const int nkt = K >> 5;
  for (int kt = 0; kt < nkt; ++kt) {
    __syncthreads();
#pragma unroll
    for (int it = 0; it < 2; ++it) {
      int cb = wv * 128 + it * 64;
      int ub = __builtin_amdgcn_readfirstlane(cb);
      int c = cb + lane;
      int row = c >> 2, slot = c & 3;
      int koff = (slot ^ ((row >> 1) & 3)) * 16;
      gll16((const char*)A + (size_t)(m0 + row) * K2 + (size_t)kt * 64 + koff,
            (char*)At + (size_t)ub * 16);
      gll16((const char*)W + (size_t)(n0 + row) * K2 + (size_t)kt * 64 + koff,
            (char*)Wt + (size_t)ub * 16);
    }
    __syncthreads();
    u32x4 Af[4], Wf[4];
#pragma unroll
    for (int i = 0; i < 4; ++i) {
      int row = wr * 64 + i * 16 + col;
      int sc = hi4 ^ ((row >> 1) & 3);
      Af[i] = *(const u32x4*)((const char*)At + (size_t)row * 64 + (size_t)sc * 16);
    }
#pragma unroll
    for (int j = 0; j < 4; ++j) {
      int row = wc * 64 + j * 16 + col;
      int sc = hi4 ^ ((row >> 1) & 3);
      Wf[j] = *(const u32x4*)((const char*)Wt + (size_t)row * 64 + (size_t)sc * 16);
    }
#pragma unroll
    for (int i = 0; i < 4; ++i)
#pragma unroll
      for (int j = 0; j < 4; ++j)
        acc[i][j] = MFMA16(as_bf(Af[i]), as_bf(Wf[j]), acc[i][j]);
  }
#pragma unroll
  for (int i = 0; i < 4; ++i) {
#pragma unroll
    for (int j = 0; j < 4; ++j) {
      int n = n0 + wc * 64 + j * 16 + col;
      float bv = bias[n];
#pragma unroll
      for (int jj = 0; jj < 4; ++jj) {
        int m = m0 + wr * 64 + i * 16 + hi4 * 4 + jj;
        float v = acc[i][j][jj] + bv;
        out[(size_t)(m & 511) * (32 * 3072) + (size_t)(m >> 9) * 3072 + n] = f2bf(v);
      }
    }
  }
}

// ---------------- converters (single launch, 4 regions) ----------------
__global__ void cvt_all_kernel(const float* __restrict__ x, u16* __restrict__ xbf,
                               const float* __restrict__ Wx, u16* __restrict__ Wxb,
                               const float* __restrict__ Wh, u16* __restrict__ Whb,
                               const float* __restrict__ Why, u16* __restrict__ Whyb) {
  int wg = (int)blockIdx.x;
  const float* src; u16* dst; int base;
  if (wg < 8192)       { src = x;   dst = xbf;  base = wg; }
  else if (wg < 11264) { src = Wx;  dst = Wxb;  base = wg - 8192; }
  else if (wg < 14336) { src = Wh;  dst = Whb;  base = wg - 11264; }
  else                 { src = Why; dst = Whyb; base = wg - 14336; }
  int i = (base * 256 + (int)threadIdx.x) * 8;  // exact multiples, no tails
  float4 a = *(const float4*)(src + i);
  float4 b = *(const float4*)(src + i + 4);
  union { u16 o[8]; u32x4 q; } u;
  u.o[0] = f2bf(a.x); u.o[1] = f2bf(a.y); u.o[2] = f2bf(a.z); u.o[3] = f2bf(a.w);
  u.o[4] = f2bf(b.x); u.o[5] = f2bf(b.y); u.o[6] = f2bf(b.z); u.o[7] = f2bf(b.w);
  *(u32x4*)(dst + i) = u.q;
}

// h0 init: layer0 -> h0ring slot 3 (per group), layer1 -> h1ring slot 3 (per group)
__global__ void h0cvt_kernel(const float* __restrict__ h0, u16* __restrict__ h0ring,
                             u16* __restrict__ h1ring) {
  int i = (int)blockIdx.x * 256 + (int)threadIdx.x;  // 0..32767
  if (i < 32768) {
    int b = i >> 10, j = i & 1023;
    int g2 = b >> 4, bl = b & 15;
    h0ring[g2 * 65536 + 3 * 16384 + bl * 1024 + j] = f2bf(h0[b * 2048 + j]);
    h1ring[g2 * 65536 + 3 * 16384 + bl * 1024 + j] = f2bf(h0[b * 2048 + 1024 + j]);
  }
}

// ---------------- host ----------------
extern "C" void kernel_launch(void* const* d_in, const int* in_sizes, int n_in,
                              void* d_out, int out_size, void* d_ws, size_t ws_size,
                              hipStream_t stream) {
  const float* x   = (const float*)d_in[0];
  const float* h0  = (const float*)d_in[1];
  const float* Wx  = (const float*)d_in[2];
  const float* bx  = (const float*)d_in[3];
  const float* Wh  = (const float*)d_in[4];
  const float* Why = (const float*)d_in[5];
  const float* bhy = (const float*)d_in[6];
  float* out = (float*)d_out;
  float* hidden = out + (size_t)32 * 512 * 1024;

  char* ws = (char*)d_ws;
  u16* xproj  = (u16*)ws;  ws += (size_t)512 * 32 * 3072 * 2;   // 100.7 MB
  u16* xbf    = (u16*)ws;  ws += (size_t)32 * 512 * 1024 * 2;   // 33.6 MB
  u16* Wxb    = (u16*)ws;  ws += (size_t)2 * 3072 * 1024 * 2;   // 12.6 MB
  u16* Whb    = (u16*)ws;  ws += (size_t)2 * 3072 * 1024 * 2;   // 12.6 MB
  u16* Whyb   = (u16*)ws;  ws += (size_t)1024 * 1024 * 2;       // 2.1 MB
  u16* h0ring = (u16*)ws;  ws += 2 * 4 * 16384 * 2;             // 256 KB
  u16* h1ring = (u16*)ws;  ws += 2 * 4 * 16384 * 2;             // 256 KB
  u16* rh0    = (u16*)ws;  ws += 2 * 16384 * 2;
  u16* rh1    = (u16*)ws;  ws += 2 * 16384 * 2;
  float* z0_t = (float*)ws; ws += 2 * 16384 * 4;                // 128 KB
  float* z1_t = (float*)ws; ws += 2 * 16384 * 4;
  u16* xp1t   = (u16*)ws;  ws += (size_t)2 * 4 * 3072 * 16 * 2; // 768 KB
  int* bar    = (int*)ws;  ws += 32768;

  // all f32->bf16 conversions in one launch (exact sizes, no tails)
  cvt_all_kernel<<<14848, 256, 0, stream>>>(x, xbf, Wx, Wxb, Wh, Whb, Why, Whyb);

  // layer0 x-projection (big GEMM)
  gemm_bt_kernel<<<dim3(3072 / 128, 16384 / 128), 256, 0, stream>>>(
      xbf, Wxb, bx, xproj, 16384, 3072, 1024);
  (void)hipMemsetAsync(bar, 0, 32768, stream);
  h0cvt_kernel<<<128, 256, 0, stream>>>(h0, h0ring, h1ring);

  // pipelined recurrence: layer0 + layer1-xproj + layer1 + output projection
  gru_pipe_kernel<<<80, 512, 0, stream>>>(
      xproj, Whb, Wxb + (size_t)3072 * 1024, bx, h0,
      h0ring, h1ring, rh0, rh1, z0_t, z1_t, xp1t,
      Whyb, bhy, out, hidden, bar);
}